// Round 5
// baseline (302.916 us; speedup 1.0000x reference)
//
#include <hip/hip_runtime.h>

// Problem: B=8, F=16, N=2048
//   w[b,i,j] = exp(-beta^2 * min(p_i,p_j) * (n_i + n_j - 2*<x_i,x_j>))
//   p_i = exp(2*alpha*log(emb[b,4,i])),  n_i = sum_f emb[b,f,i]^2
// Output 134 MB fp32 -> HBM-write-bound (~21 us floor at 6.3 TB/s).
//
// R2: 128x128 tile, 8x8/thread: neutral -> not LDS-bound.
// R4: nontemporal stores: neutral -> not L2-thrash-bound.
// R5: kernel ~35us = ~10us compute + ~21us stores SERIALIZED (all stores
//     burst after full accumulation). Split into 2 row-half chunks:
//     compute+store chunk 0, then chunk 1 -> stores drain during chunk-1
//     compute. Predict kernel ~25us.

#define BATCH 8
#define FDIM 16
#define NPT 2048
#define TILE 128

typedef float vfloat4 __attribute__((ext_vector_type(4)));

__global__ __launch_bounds__(256, 4) void qcd_aware_kernel(
    const float* __restrict__ emb,
    const float* __restrict__ alpha_p,
    const float* __restrict__ beta_p,
    float* __restrict__ out)
{
    __shared__ float As[FDIM][TILE];
    __shared__ float Bs[FDIM][TILE];
    __shared__ float nI[TILE], nJ[TILE], qI[TILE], qJ[TILE];

    const int b  = blockIdx.z;
    const int i0 = blockIdx.y * TILE;
    const int j0 = blockIdx.x * TILE;
    const int tid = threadIdx.x;

    // ---- stage A (i-cols) and B (j-cols): 16x128 floats each, float4 ----
    {
        const int f = tid >> 4;          // 0..15
        const int c = (tid & 15) * 4;    // 0,4,...,60
        const float* src = emb + ((size_t)b * FDIM + f) * NPT;
        *(float4*)&As[f][c]      = *(const float4*)(src + i0 + c);
        *(float4*)&As[f][c + 64] = *(const float4*)(src + i0 + c + 64);
        *(float4*)&Bs[f][c]      = *(const float4*)(src + j0 + c);
        *(float4*)&Bs[f][c + 64] = *(const float4*)(src + j0 + c + 64);
    }
    __syncthreads();

    const float alpha2 = 2.0f * alpha_p[0];
    const float beta   = beta_p[0];
    // q = -beta^2 * log2(e) * p   (negative scale: min(p_i,p_j) -> max(q_i,q_j))
    const float qscale = -(beta * beta) * 1.4426950408889634f;

    // ---- per-edge precompute: squared norm + scaled pow-momentum ----
    {
        const int e = tid & 127;
        float s = 0.f;
        if (tid < TILE) {
            #pragma unroll
            for (int f = 0; f < FDIM; ++f) { float v = As[f][e]; s += v * v; }
            nI[e] = s;
            qI[e] = qscale * __expf(alpha2 * __logf(As[4][e]));
        } else {
            #pragma unroll
            for (int f = 0; f < FDIM; ++f) { float v = Bs[f][e]; s += v * v; }
            nJ[e] = s;
            qJ[e] = qscale * __expf(alpha2 * __logf(Bs[4][e]));
        }
    }
    __syncthreads();

    const int tx4 = (tid & 15) * 4;   // 0..60
    const int ty4 = (tid >> 4) * 4;   // 0..60

    // ---- column-side epilogue params (shared by both chunks) ----
    float nj[8], qj[8];
    #pragma unroll
    for (int jj = 0; jj < 4; ++jj) {
        nj[jj]     = nJ[tx4 + jj];      qj[jj]     = qJ[tx4 + jj];
        nj[jj + 4] = nJ[tx4 + 64 + jj]; qj[jj + 4] = qJ[tx4 + 64 + jj];
    }

    // ---- two chunks: rows {ty4..+3} then {ty4+64..+3}; store each chunk
    //      as soon as it's done so stores drain during the next chunk ----
    #pragma unroll
    for (int ih = 0; ih < 2; ++ih) {
        const int rbase = ih * 64 + ty4;

        float acc[4][8] = {};
        #pragma unroll
        for (int f = 0; f < FDIM; ++f) {
            const float4 a0 = *(const float4*)&As[f][rbase];
            const float4 b0 = *(const float4*)&Bs[f][tx4];
            const float4 b1 = *(const float4*)&Bs[f][tx4 + 64];
            const float av[4] = {a0.x, a0.y, a0.z, a0.w};
            const float bv[8] = {b0.x, b0.y, b0.z, b0.w, b1.x, b1.y, b1.z, b1.w};
            #pragma unroll
            for (int ii = 0; ii < 4; ++ii)
                #pragma unroll
                for (int jj = 0; jj < 8; ++jj)
                    acc[ii][jj] = fmaf(av[ii], bv[jj], acc[ii][jj]);
        }

        #pragma unroll
        for (int ii = 0; ii < 4; ++ii) {
            const int il = rbase + ii;
            const float ni = nI[il];
            const float qi = qI[il];
            const size_t rowp = ((size_t)b * NPT + (size_t)(i0 + il)) * NPT + j0;
            #pragma unroll
            for (int jh = 0; jh < 2; ++jh) {
                vfloat4 w;
                #pragma unroll
                for (int jj = 0; jj < 4; ++jj) {
                    const int jr = jh * 4 + jj;
                    const float s = ni + nj[jr];
                    const float d = fmaf(-2.0f, acc[ii][jh * 4 + jj], s);
                    // exponent = max(qi,qj)*d in [-24, 0] -> raw v_exp_f32 safe
                    w[jj] = __builtin_amdgcn_exp2f(fmaxf(qi, qj[jr]) * d);
                }
                __builtin_nontemporal_store(w, (vfloat4*)(out + rowp + jh * 64 + tx4));
            }
        }
    }
}

extern "C" void kernel_launch(void* const* d_in, const int* in_sizes, int n_in,
                              void* d_out, int out_size, void* d_ws, size_t ws_size,
                              hipStream_t stream) {
    const float* emb     = (const float*)d_in[0];
    const float* alpha_p = (const float*)d_in[1];
    const float* beta_p  = (const float*)d_in[2];
    float* out = (float*)d_out;

    dim3 grid(NPT / TILE, NPT / TILE, BATCH);  // 16 x 16 x 8
    dim3 block(256);
    qcd_aware_kernel<<<grid, block, 0, stream>>>(emb, alpha_p, beta_p, out);
}

// Round 6
// 140.603 us; speedup vs baseline: 2.1544x; 2.1544x over previous
//
#include <hip/hip_runtime.h>

// Problem: B=8, F=16, N=2048
//   w[b,i,j] = exp(-beta^2 * min(p_i,p_j) * (n_i + n_j - 2*<x_i,x_j>))
//   p_i = exp(2*alpha*log(emb[b,4,i])),  n_i = sum_f emb[b,f,i]^2
// Output 134 MB fp32; fixed harness poison ~104 us; kernel floor ~22 us.
//
// R2: 128x128 tile, 8x8/thread: 141 us total (kernel ~37 us).
// R4: nt stores: neutral. R5: chunk-split + nt: 4.2x write amplification,
//     218 MB phantom FETCH, 206 us kernel -> REVERTED (plain stores, no chunk).
// R6: fix the measured 4.2M LDS bank conflicts (8-way on ds_write_b128
//     staging): stage via linear ds_write_b64 (word = 2*tid, stride-1,
//     conflict-free); global side reads one f-row per wave as float2
//     (512B/wave, coalesced).

#define BATCH 8
#define FDIM 16
#define NPT 2048
#define TILE 128

__global__ __launch_bounds__(256, 4) void qcd_aware_kernel(
    const float* __restrict__ emb,
    const float* __restrict__ alpha_p,
    const float* __restrict__ beta_p,
    float* __restrict__ out)
{
    __shared__ float As[FDIM][TILE];
    __shared__ float Bs[FDIM][TILE];
    __shared__ float nI[TILE], nJ[TILE], qI[TILE], qJ[TILE];

    const int b  = blockIdx.z;
    const int i0 = blockIdx.y * TILE;
    const int j0 = blockIdx.x * TILE;
    const int tid = threadIdx.x;

    // ---- stage A (i-cols) and B (j-cols): 16x128 floats each ----
    // Linear word order: thread writes words {2*tid + 512*r} -> stride-1
    // ds_write_b64, zero bank conflicts. Each 64-lane wave covers exactly
    // one f-row (128 words): f = w>>7, i = w&127; global float2 coalesced.
    {
        float* AsF = &As[0][0];
        float* BsF = &Bs[0][0];
        const float* base = emb + (size_t)b * FDIM * NPT;
        #pragma unroll
        for (int r = 0; r < 4; ++r) {
            const int w = 2 * tid + 512 * r;     // word in [0, 2048)
            const int f = w >> 7;
            const int i = w & 127;
            *(float2*)&AsF[w] = *(const float2*)(base + (size_t)f * NPT + i0 + i);
            *(float2*)&BsF[w] = *(const float2*)(base + (size_t)f * NPT + j0 + i);
        }
    }
    __syncthreads();

    const float alpha2 = 2.0f * alpha_p[0];
    const float beta   = beta_p[0];
    // q = -beta^2 * log2(e) * p   (negative scale: min(p_i,p_j) -> max(q_i,q_j))
    const float qscale = -(beta * beta) * 1.4426950408889634f;

    // ---- per-edge precompute: squared norm + scaled pow-momentum ----
    {
        const int e = tid & 127;
        float s = 0.f;
        if (tid < TILE) {
            #pragma unroll
            for (int f = 0; f < FDIM; ++f) { float v = As[f][e]; s += v * v; }
            nI[e] = s;
            qI[e] = qscale * __expf(alpha2 * __logf(As[4][e]));
        } else {
            #pragma unroll
            for (int f = 0; f < FDIM; ++f) { float v = Bs[f][e]; s += v * v; }
            nJ[e] = s;
            qJ[e] = qscale * __expf(alpha2 * __logf(Bs[4][e]));
        }
    }
    __syncthreads();

    // ---- 8x8 micro-tile per thread: rows {ty4, ty4+64}, cols {tx4, tx4+64} ----
    const int tx4 = (tid & 15) * 4;   // 0..60
    const int ty4 = (tid >> 4) * 4;   // 0..60

    float acc[8][8] = {};
    #pragma unroll
    for (int f = 0; f < FDIM; ++f) {
        const float4 a0 = *(const float4*)&As[f][ty4];
        const float4 a1 = *(const float4*)&As[f][ty4 + 64];
        const float4 b0 = *(const float4*)&Bs[f][tx4];
        const float4 b1 = *(const float4*)&Bs[f][tx4 + 64];
        const float av[8] = {a0.x, a0.y, a0.z, a0.w, a1.x, a1.y, a1.z, a1.w};
        const float bv[8] = {b0.x, b0.y, b0.z, b0.w, b1.x, b1.y, b1.z, b1.w};
        #pragma unroll
        for (int ii = 0; ii < 8; ++ii)
            #pragma unroll
            for (int jj = 0; jj < 8; ++jj)
                acc[ii][jj] = fmaf(av[ii], bv[jj], acc[ii][jj]);
    }

    // ---- epilogue ----
    float nj[8], qj[8];
    #pragma unroll
    for (int jj = 0; jj < 4; ++jj) {
        nj[jj]     = nJ[tx4 + jj];      qj[jj]     = qJ[tx4 + jj];
        nj[jj + 4] = nJ[tx4 + 64 + jj]; qj[jj + 4] = qJ[tx4 + 64 + jj];
    }

    #pragma unroll
    for (int ih = 0; ih < 2; ++ih) {
        #pragma unroll
        for (int ii = 0; ii < 4; ++ii) {
            const int il = ih * 64 + ty4 + ii;
            const float ni = nI[il];
            const float qi = qI[il];
            const size_t rowp = ((size_t)b * NPT + (size_t)(i0 + il)) * NPT + j0;
            #pragma unroll
            for (int jh = 0; jh < 2; ++jh) {
                float4 w;
                float* wv = (float*)&w;
                #pragma unroll
                for (int jj = 0; jj < 4; ++jj) {
                    const int jr = jh * 4 + jj;
                    const float s = ni + nj[jr];
                    const float d = fmaf(-2.0f, acc[ih * 4 + ii][jh * 4 + jj], s);
                    // exponent = max(qi,qj)*d in [-24, 0] -> raw v_exp_f32 safe
                    wv[jj] = __builtin_amdgcn_exp2f(fmaxf(qi, qj[jr]) * d);
                }
                *(float4*)(out + rowp + jh * 64 + tx4) = w;
            }
        }
    }
}

extern "C" void kernel_launch(void* const* d_in, const int* in_sizes, int n_in,
                              void* d_out, int out_size, void* d_ws, size_t ws_size,
                              hipStream_t stream) {
    const float* emb     = (const float*)d_in[0];
    const float* alpha_p = (const float*)d_in[1];
    const float* beta_p  = (const float*)d_in[2];
    float* out = (float*)d_out;

    dim3 grid(NPT / TILE, NPT / TILE, BATCH);  // 16 x 16 x 8
    dim3 block(256);
    qcd_aware_kernel<<<grid, block, 0, stream>>>(emb, alpha_p, beta_p, out);
}